// Round 3
// baseline (143.518 us; speedup 1.0000x reference)
//
#include <hip/hip_runtime.h>

constexpr int Dz = 96, Hy = 160, Wx = 160;
constexpr int NVOX = Dz * Hy * Wx;

// Stage-1 footprint of a 32d x 32w x 2h block (exact: x=53d/32, z=19w/32, y=159h/160)
constexpr int ZSPAN = 20, YSPAN = 3, XSPAN = 53, XPAD = 55;  // odd pad: z-stride 165 mod 32 = 5 (coprime)
constexpr int NL = ZSPAN * YSPAN * XSPAN;  // 3180
constexpr int NLOAD = (NL + 255) / 256;    // 13

__global__ __launch_bounds__(256) void st_fused_kernel(
    const float* __restrict__ src,
    const float* __restrict__ flows,
    const float* __restrict__ rfp,
    float* __restrict__ out)
{
    __shared__ float raw[ZSPAN][YSPAN][XPAD];
    const int t  = threadIdx.x;
    const int w0 = blockIdx.x * 32;
    const int d0 = blockIdx.y * 32;
    const int h0 = blockIdx.z * 2;
    const float rf = *rfp;

    const int Z0 = (19 * w0) >> 5;     // integral (w0 % 32 == 0)
    const int X0 = (53 * d0) >> 5;     // integral (d0 % 32 == 0)
    const int YB = (159 * h0) / 160;

    // ---- hoisted load-slot decomposition (p-invariant) ----
    int goff[NLOAD], loff[NLOAD];
#pragma unroll
    for (int u = 0; u < NLOAD; ++u) {
        int i = t + u * 256;
        int ic = i < NL ? i : 0;
        int r  = ic / XSPAN;
        int x  = ic - r * XSPAN;
        int z  = r / YSPAN;
        int y  = r - z * YSPAN;
        goff[u] = (z * Hy + y) * Wx + x;          // rel to (Z0,YB,X0) corner
        loff[u] = (z * YSPAN + y) * XPAD + x;     // LDS dword offset
    }
    const bool last_act = t < (NL - (NLOAD - 1) * 256);

    // ---- compute-phase constants: lanes vary w (stage-1 z axis) ----
    const int wl = t & 31;
    const int w  = w0 + wl;
    const float zf = (float)(19 * w) * (1.0f / 32.0f);   // exact
    const int   z0i = (int)zf;
    const float fz  = zf - (float)z0i;
    const int   zz  = z0i - Z0;                          // 0..18
    const float wz0 = 1.0f - fz, wz1 = fz;

    const int dbase = t >> 5;                            // 0..7
    int xx[4]; float wx0[4], wx1[4];
#pragma unroll
    for (int k = 0; k < 4; ++k) {
        const int d = d0 + dbase + 8 * k;
        const float xf = (float)(53 * d) * (1.0f / 32.0f);  // exact
        const int x0i = (int)xf;
        const float fx = xf - (float)x0i;
        xx[k]  = x0i - X0;                               // 0..51
        wx0[k] = 1.0f - fx; wx1[k] = fx;
    }

    float wyr[2][3];
#pragma unroll
    for (int j = 0; j < 2; ++j) {
        const int h = h0 + j;
        const float yf = (float)h * (159.0f / 160.0f);
        const int y0i = (int)yf;
        const float fy = yf - (float)y0i;
        const int yrel = y0i - YB;                       // 0 or 1
        const float a = 1.0f - fy, b = fy;
        wyr[j][0] = (yrel == 0) ? a : 0.0f;
        wyr[j][1] = (yrel == 0) ? b : a;
        wyr[j][2] = (yrel == 0) ? 0.0f : b;
    }

    float acc[3][4][2];
#pragma unroll
    for (int c = 0; c < 3; ++c)
#pragma unroll
        for (int k = 0; k < 4; ++k)
#pragma unroll
            for (int j = 0; j < 2; ++j) acc[c][k][j] = 0.0f;

    float* lds = &raw[0][0][0];

#pragma unroll
    for (int p = 0; p < 9; ++p) {
        const float* fb = flows + (size_t)p * NVOX + (Z0 * Hy + YB) * Wx + X0;
#pragma unroll
        for (int u = 0; u < NLOAD - 1; ++u)
            lds[loff[u]] = fb[goff[u]];
        if (last_act) lds[loff[NLOAD - 1]] = fb[goff[NLOAD - 1]];
        __syncthreads();

        // z-interp into registers (x-pair kept for later x-interp)
        float zv0[3][4], zv1[3][4];
#pragma unroll
        for (int yy = 0; yy < 3; ++yy)
#pragma unroll
            for (int k = 0; k < 4; ++k) {
                const float a0 = raw[zz][yy][xx[k]];
                const float a1 = raw[zz][yy][xx[k] + 1];
                const float b0 = raw[zz + 1][yy][xx[k]];
                const float b1 = raw[zz + 1][yy][xx[k] + 1];
                zv0[yy][k] = wz0 * a0 + wz1 * b0;
                zv1[yy][k] = wz0 * a1 + wz1 * b1;
            }

        const int c = p % 3;  // p is unrolled -> static index
#pragma unroll
        for (int j = 0; j < 2; ++j)
#pragma unroll
            for (int k = 0; k < 4; ++k) {
                const float yv0 = wyr[j][0] * zv0[0][k] + wyr[j][1] * zv0[1][k] + wyr[j][2] * zv0[2][k];
                const float yv1 = wyr[j][0] * zv1[0][k] + wyr[j][1] * zv1[1][k] + wyr[j][2] * zv1[2][k];
                acc[c][k][j] += wx0[k] * yv0 + wx1[k] * yv1;
            }
        __syncthreads();
    }

    // ---- stage 2: sample src (zeros mode), lanes vary w -> coalesced store ----
#pragma unroll
    for (int j = 0; j < 2; ++j) {
        const int h = h0 + j;
#pragma unroll
        for (int k = 0; k < 4; ++k) {
            const int d = d0 + dbase + 8 * k;
            const float f0 = (float)d + acc[0][k][j] * rf;   // -> x axis of src
            const float f1 = (float)h + acc[1][k][j] * rf;   // -> y axis
            const float f2 = (float)w + acc[2][k][j] * rf;   // -> z axis

            const float xs = f0 * (159.0f / 95.0f);
            const float ys = f1;
            const float zs = f2 * (95.0f / 159.0f);

            const float xs0f = floorf(xs), ys0f = floorf(ys), zs0f = floorf(zs);
            const float gx = xs - xs0f, gy = ys - ys0f, gz = zs - zs0f;
            const int xi0 = (int)xs0f, yi0 = (int)ys0f, zi0 = (int)zs0f;
            const int xi1 = xi0 + 1, yi1 = yi0 + 1, zi1 = zi0 + 1;

            auto samp = [&](int zi, int yi, int xi, float wt) -> float {
                bool valid = ((unsigned)zi < (unsigned)Dz)
                           & ((unsigned)yi < (unsigned)Hy)
                           & ((unsigned)xi < (unsigned)Wx);
                int zc = min(max(zi, 0), Dz - 1);
                int yc = min(max(yi, 0), Hy - 1);
                int xc = min(max(xi, 0), Wx - 1);
                float v = src[(zc * Hy + yc) * Wx + xc];
                return valid ? wt * v : 0.0f;
            };

            float r = samp(zi0, yi0, xi0, (1.0f - gz) * (1.0f - gy) * (1.0f - gx))
                    + samp(zi0, yi0, xi1, (1.0f - gz) * (1.0f - gy) * gx)
                    + samp(zi0, yi1, xi0, (1.0f - gz) * gy * (1.0f - gx))
                    + samp(zi0, yi1, xi1, (1.0f - gz) * gy * gx)
                    + samp(zi1, yi0, xi0, gz * (1.0f - gy) * (1.0f - gx))
                    + samp(zi1, yi0, xi1, gz * (1.0f - gy) * gx)
                    + samp(zi1, yi1, xi0, gz * gy * (1.0f - gx))
                    + samp(zi1, yi1, xi1, gz * gy * gx);

            out[(d * Hy + h) * Wx + w] = r;
        }
    }
}

extern "C" void kernel_launch(void* const* d_in, const int* in_sizes, int n_in,
                              void* d_out, int out_size, void* d_ws, size_t ws_size,
                              hipStream_t stream) {
    const float* src   = (const float*)d_in[0];
    const float* flows = (const float*)d_in[1];
    const float* rfp   = (const float*)d_in[2];
    float* out = (float*)d_out;

    dim3 grid(Wx / 32, Dz / 32, Hy / 2);  // (5, 3, 80) = 1200 blocks
    st_fused_kernel<<<grid, 256, 0, stream>>>(src, flows, rfp, out);
}

// Round 4
// 105.687 us; speedup vs baseline: 1.3580x; 1.3580x over previous
//
#include <hip/hip_runtime.h>

constexpr int Dz = 96, Hy = 160, Wx = 160;
constexpr int NVOX = Dz * Hy * Wx;

// Stage-1 footprint of a 32d x 32w x 2h block (x=53d/32, z=19w/32, y=159h/160)
constexpr int ZSPAN = 20, YSPAN = 3, XSPAN = 53, XPAD = 55;  // odd strides: z-stride 165, y-stride 55
constexpr int NL = ZSPAN * YSPAN * XSPAN;   // 3180 loaded floats per plane
constexpr int NLOAD = (NL + 255) / 256;     // 13 slots/thread
constexpr int PLANE = ZSPAN * YSPAN * XPAD; // 3300 floats per LDS buffer

__global__ __launch_bounds__(256, 4) void st_fused_kernel(
    const float* __restrict__ src,
    const float* __restrict__ flows,
    const float* __restrict__ rfp,
    float* __restrict__ out)
{
    __shared__ float raw[2][ZSPAN][YSPAN][XPAD];   // 26.4 KB double buffer
    const int t = threadIdx.x;

    // XCD-aware bijective swizzle: 1200 blocks = 8 XCDs x 150
    const int bid = blockIdx.x;
    const int swz = (bid & 7) * 150 + (bid >> 3);
    const int bx = swz % 5;
    const int rest = swz / 5;
    const int by = rest % 3;
    const int bz = rest / 3;
    const int w0 = bx * 32, d0 = by * 32, h0 = bz * 2;
    const float rf = *rfp;

    const int Z0 = (19 * w0) >> 5;
    const int X0 = (53 * d0) >> 5;
    const int YB = (159 * h0) / 160;

    // ---- hoisted load-slot decomposition (plane-invariant), byte offsets ----
    int goffb[NLOAD], loffb[NLOAD];
#pragma unroll
    for (int u = 0; u < NLOAD; ++u) {
        int i = t + u * 256;
        int ic = i < NL ? i : 0;
        int r = ic / XSPAN;
        int x = ic - r * XSPAN;
        int z = r / YSPAN;
        int y = r - z * YSPAN;
        goffb[u] = ((z * Hy + y) * Wx + x) * 4;
        loffb[u] = ((z * YSPAN + y) * XPAD + x) * 4;
    }
    const bool last_act = t < (NL - (NLOAD - 1) * 256);  // t < 108
    const size_t baseoff = ((size_t)(Z0 * Hy + YB) * Wx + X0) * 4;

    float rbuf[NLOAD];
    auto stage_load = [&](int p) {
        const char* fb = (const char*)flows + (size_t)p * NVOX * 4 + baseoff;
#pragma unroll
        for (int u = 0; u < NLOAD; ++u)
            rbuf[u] = *(const float*)(fb + goffb[u]);
    };
    auto stage_write = [&](float* lb) {
        char* l = (char*)lb;
#pragma unroll
        for (int u = 0; u < NLOAD - 1; ++u)
            *(float*)(l + loffb[u]) = rbuf[u];
        if (last_act) *(float*)(l + loffb[NLOAD - 1]) = rbuf[NLOAD - 1];
    };

    // ---- compute-phase constants: lanes vary w (stage-1 z axis) ----
    const int wl = t & 31;
    const int w = w0 + wl;
    const float zf = (float)(19 * w) * (1.0f / 32.0f);
    const int z0i = (int)zf;
    const float fz = zf - (float)z0i;
    const int zz = z0i - Z0;                    // 0..18
    const float wz0 = 1.0f - fz, wz1 = fz;

    const int dbase = t >> 5;                   // 0..7
    int xx[4]; float wx0[4], wx1[4];
#pragma unroll
    for (int k = 0; k < 4; ++k) {
        const int d = d0 + dbase + 8 * k;
        const float xf = (float)(53 * d) * (1.0f / 32.0f);
        const int x0i = (int)xf;
        const float fx = xf - (float)x0i;
        xx[k] = x0i - X0;                       // 0..51
        wx0[k] = 1.0f - fx; wx1[k] = fx;
    }

    float wyr[2][3];
#pragma unroll
    for (int j = 0; j < 2; ++j) {
        const int h = h0 + j;
        const float yf = (float)h * (159.0f / 160.0f);
        const int y0i = (int)yf;
        const float fy = yf - (float)y0i;
        const int yrel = y0i - YB;              // 0 or 1
        const float a = 1.0f - fy, b = fy;
        wyr[j][0] = (yrel == 0) ? a : 0.0f;
        wyr[j][1] = (yrel == 0) ? b : a;
        wyr[j][2] = (yrel == 0) ? 0.0f : b;
    }

    auto compute = [&](const float* lb, float (&v)[4][2]) {
        const float* zrow = lb + zz * (YSPAN * XPAD);
#pragma unroll
        for (int k = 0; k < 4; ++k) {
            float zv0[3], zv1[3];
#pragma unroll
            for (int yy = 0; yy < 3; ++yy) {
                const float* r0 = zrow + yy * XPAD + xx[k];
                const float a0 = r0[0], a1 = r0[1];
                const float b0 = r0[YSPAN * XPAD], b1 = r0[YSPAN * XPAD + 1];
                zv0[yy] = wz0 * a0 + wz1 * b0;
                zv1[yy] = wz0 * a1 + wz1 * b1;
            }
#pragma unroll
            for (int j = 0; j < 2; ++j) {
                const float yv0 = wyr[j][0] * zv0[0] + wyr[j][1] * zv0[1] + wyr[j][2] * zv0[2];
                const float yv1 = wyr[j][0] * zv1[0] + wyr[j][1] * zv1[1] + wyr[j][2] * zv1[2];
                v[k][j] = wx0[k] * yv0 + wx1[k] * yv1;
            }
        }
    };

    float accA[4][2], accB[4][2], accC[4][2];
#pragma unroll
    for (int k = 0; k < 4; ++k)
#pragma unroll
        for (int j = 0; j < 2; ++j) { accA[k][j] = 0.f; accB[k][j] = 0.f; accC[k][j] = 0.f; }

    auto accadd = [&](int c, const float (&v)[4][2]) {
        if (c == 0) {
#pragma unroll
            for (int k = 0; k < 4; ++k) { accA[k][0] += v[k][0]; accA[k][1] += v[k][1]; }
        } else if (c == 1) {
#pragma unroll
            for (int k = 0; k < 4; ++k) { accB[k][0] += v[k][0]; accB[k][1] += v[k][1]; }
        } else {
#pragma unroll
            for (int k = 0; k < 4; ++k) { accC[k][0] += v[k][0]; accC[k][1] += v[k][1]; }
        }
    };

    float* lds0 = &raw[0][0][0][0];
    float* lds1 = &raw[1][0][0][0];

    // ---- double-buffered plane pipeline: 1 barrier/plane, loads hide under compute ----
    stage_load(0);
    stage_write(lds0);
#pragma unroll 1
    for (int pp = 0; pp < 4; ++pp) {
        const int p = 2 * pp;
        __syncthreads();                 // buf0 (plane p) ready
        stage_load(p + 1);               // issue; latency hides under compute
        { float v[4][2]; compute(lds0, v); accadd(p % 3, v); }
        stage_write(lds1);               // vmcnt drain via rbuf dependency
        __syncthreads();                 // buf1 (plane p+1) ready
        stage_load(p + 2);
        { float v[4][2]; compute(lds1, v); accadd((p + 1) % 3, v); }
        stage_write(lds0);
    }
    __syncthreads();                     // buf0 (plane 8) ready
    { float v[4][2]; compute(lds0, v); accadd(2, v); }

    // ---- stage 2: sample src (zeros mode), lanes vary w -> coalesced store ----
#pragma unroll
    for (int j = 0; j < 2; ++j) {
        const int h = h0 + j;
#pragma unroll
        for (int k = 0; k < 4; ++k) {
            const int d = d0 + dbase + 8 * k;
            const float a0 = (k == 0 ? accA[0][j] : k == 1 ? accA[1][j] : k == 2 ? accA[2][j] : accA[3][j]);
            const float a1 = (k == 0 ? accB[0][j] : k == 1 ? accB[1][j] : k == 2 ? accB[2][j] : accB[3][j]);
            const float a2 = (k == 0 ? accC[0][j] : k == 1 ? accC[1][j] : k == 2 ? accC[2][j] : accC[3][j]);
            const float f0 = (float)d + a0 * rf;   // -> x axis of src
            const float f1 = (float)h + a1 * rf;   // -> y axis
            const float f2 = (float)w + a2 * rf;   // -> z axis

            const float xs = f0 * (159.0f / 95.0f);
            const float ys = f1;
            const float zs = f2 * (95.0f / 159.0f);

            const float xs0f = floorf(xs), ys0f = floorf(ys), zs0f = floorf(zs);
            const float gx = xs - xs0f, gy = ys - ys0f, gz = zs - zs0f;
            const int xi0 = (int)xs0f, yi0 = (int)ys0f, zi0 = (int)zs0f;
            const int xi1 = xi0 + 1, yi1 = yi0 + 1, zi1 = zi0 + 1;

            auto samp = [&](int zi, int yi, int xi, float wt) -> float {
                bool valid = ((unsigned)zi < (unsigned)Dz)
                           & ((unsigned)yi < (unsigned)Hy)
                           & ((unsigned)xi < (unsigned)Wx);
                int zc = min(max(zi, 0), Dz - 1);
                int yc = min(max(yi, 0), Hy - 1);
                int xc = min(max(xi, 0), Wx - 1);
                float v = src[(zc * Hy + yc) * Wx + xc];
                return valid ? wt * v : 0.0f;
            };

            float r = samp(zi0, yi0, xi0, (1.0f - gz) * (1.0f - gy) * (1.0f - gx))
                    + samp(zi0, yi0, xi1, (1.0f - gz) * (1.0f - gy) * gx)
                    + samp(zi0, yi1, xi0, (1.0f - gz) * gy * (1.0f - gx))
                    + samp(zi0, yi1, xi1, (1.0f - gz) * gy * gx)
                    + samp(zi1, yi0, xi0, gz * (1.0f - gy) * (1.0f - gx))
                    + samp(zi1, yi0, xi1, gz * (1.0f - gy) * gx)
                    + samp(zi1, yi1, xi0, gz * gy * (1.0f - gx))
                    + samp(zi1, yi1, xi1, gz * gy * gx);

            out[(d * Hy + h) * Wx + w] = r;
        }
    }
}

extern "C" void kernel_launch(void* const* d_in, const int* in_sizes, int n_in,
                              void* d_out, int out_size, void* d_ws, size_t ws_size,
                              hipStream_t stream) {
    const float* src   = (const float*)d_in[0];
    const float* flows = (const float*)d_in[1];
    const float* rfp   = (const float*)d_in[2];
    float* out = (float*)d_out;

    st_fused_kernel<<<dim3(1200), 256, 0, stream>>>(src, flows, rfp, out);
}

// Round 5
// 78.387 us; speedup vs baseline: 1.8309x; 1.3483x over previous
//
#include <hip/hip_runtime.h>
#include <stdint.h>

constexpr int Dz = 96, Hy = 160, Wx = 160;
constexpr int NVOX = Dz * Hy * Wx;

// Stage-1 footprint of a 32d x 32w x 2h block (x=53d/32, z=19w/32, y=159h/160)
constexpr int ZSPAN = 20, YSPAN = 3, XSPAN = 53;   // unpadded, i-linear LDS layout
constexpr int NL = ZSPAN * YSPAN * XSPAN;          // 3180 floats per plane
constexpr int NSLOT = (NL + 255) / 256;            // 13 load slots per thread
constexpr int LBUF = NSLOT * 256;                  // 3328 floats per buffer (tail junk ok)

typedef __attribute__((address_space(3))) float lds_f;
typedef __attribute__((address_space(1))) const void gbl_v;

__global__ __launch_bounds__(256) void st_fused_kernel(
    const float* __restrict__ src,
    const float* __restrict__ flows,
    const float* __restrict__ rfp,
    float* __restrict__ out)
{
    __shared__ float raw[2][LBUF];   // 26624 B double buffer
    const int t = threadIdx.x;

    // XCD-aware bijective swizzle: 1200 blocks = 8 XCDs x 150
    const int bid = blockIdx.x;
    const int swz = (bid & 7) * 150 + (bid >> 3);
    const int bx = swz % 5;
    const int rest = swz / 5;
    const int by = rest % 3;
    const int bz = rest / 3;
    const int w0 = bx * 32, d0 = by * 32, h0 = bz * 2;
    const float rf = *rfp;

    const int Z0 = (19 * w0) >> 5;
    const int X0 = (53 * d0) >> 5;
    const int YB = (159 * h0) / 160;

    // ---- per-lane global byte offsets for the plane footprint (plane-invariant) ----
    int goffb[NSLOT];
#pragma unroll
    for (int u = 0; u < NSLOT; ++u) {
        int i = t + u * 256;
        int ic = i < NL ? i : NL - 1;          // tail lanes: clamped dup loads (LDS junk, never read)
        int r = ic / XSPAN;
        int x = ic - r * XSPAN;
        int z = r / YSPAN;
        int y = r - z * YSPAN;
        goffb[u] = ((z * Hy + y) * Wx + x) * 4;
    }
    const size_t baseoff = ((size_t)(Z0 * Hy + YB) * Wx + X0) * 4;

    // Async global -> LDS staging: linear LDS dest (wave-uniform base + lane*4),
    // footprint gather carried by the per-lane GLOBAL address.
    auto issue_loads = [&](int p, int b) {
        const char* fb = (const char*)flows + (size_t)p * NVOX * 4 + baseoff;
#pragma unroll
        for (int u = 0; u < NSLOT; ++u) {
            __builtin_amdgcn_global_load_lds(
                (gbl_v*)(fb + goffb[u]),
                (lds_f*)&raw[b][t + u * 256],
                4, 0, 0);
        }
    };

    // ---- compute-phase constants: lanes vary w (stage-1 z axis) ----
    const int wl = t & 31;
    const int w = w0 + wl;
    const float zf = (float)(19 * w) * (1.0f / 32.0f);
    const int z0i = (int)zf;
    const float fz = zf - (float)z0i;
    const int zz = z0i - Z0;                    // 0..18
    const float wz0 = 1.0f - fz, wz1 = fz;

    const int dbase = t >> 5;                   // 0..7
    int xx[4]; float wx0[4], wx1[4];
#pragma unroll
    for (int k = 0; k < 4; ++k) {
        const int d = d0 + dbase + 8 * k;
        const float xf = (float)(53 * d) * (1.0f / 32.0f);
        const int x0i = (int)xf;
        const float fx = xf - (float)x0i;
        xx[k] = x0i - X0;                       // 0..51
        wx0[k] = 1.0f - fx; wx1[k] = fx;
    }

    float wyr[2][3];
#pragma unroll
    for (int j = 0; j < 2; ++j) {
        const int h = h0 + j;
        const float yf = (float)h * (159.0f / 160.0f);
        const int y0i = (int)yf;
        const float fy = yf - (float)y0i;
        const int yrel = y0i - YB;              // 0 or 1
        const float a = 1.0f - fy, b = fy;
        wyr[j][0] = (yrel == 0) ? a : 0.0f;
        wyr[j][1] = (yrel == 0) ? b : a;
        wyr[j][2] = (yrel == 0) ? 0.0f : b;
    }

    auto compute = [&](const float* lb, float (&v)[4][2]) {
        const float* zrow = lb + zz * (YSPAN * XSPAN);   // stride 159 ≡ -1 (mod 32): conflict-free
#pragma unroll
        for (int k = 0; k < 4; ++k) {
            float zv0[3], zv1[3];
#pragma unroll
            for (int yy = 0; yy < 3; ++yy) {
                const float* r0 = zrow + yy * XSPAN + xx[k];
                const float a0 = r0[0], a1 = r0[1];
                const float b0 = r0[YSPAN * XSPAN], b1 = r0[YSPAN * XSPAN + 1];
                zv0[yy] = wz0 * a0 + wz1 * b0;
                zv1[yy] = wz0 * a1 + wz1 * b1;
            }
#pragma unroll
            for (int j = 0; j < 2; ++j) {
                const float yv0 = wyr[j][0] * zv0[0] + wyr[j][1] * zv0[1] + wyr[j][2] * zv0[2];
                const float yv1 = wyr[j][0] * zv1[0] + wyr[j][1] * zv1[1] + wyr[j][2] * zv1[2];
                v[k][j] = wx0[k] * yv0 + wx1[k] * yv1;
            }
        }
    };

    float accA[4][2], accB[4][2], accC[4][2];
#pragma unroll
    for (int k = 0; k < 4; ++k)
#pragma unroll
        for (int j = 0; j < 2; ++j) { accA[k][j] = 0.f; accB[k][j] = 0.f; accC[k][j] = 0.f; }

    // ---- plane pipeline: 1 barrier/plane; p+1 loads in flight under compute of p ----
    issue_loads(0, 0);
#pragma unroll
    for (int p = 0; p < 9; ++p) {
        __syncthreads();                        // vmcnt(0) drain publishes plane p
        if (p < 8) issue_loads(p + 1, (p + 1) & 1);
        float v[4][2];
        compute(&raw[p & 1][0], v);
        const int c = p % 3;                    // static (p unrolled)
        if (c == 0) {
#pragma unroll
            for (int k = 0; k < 4; ++k) { accA[k][0] += v[k][0]; accA[k][1] += v[k][1]; }
        } else if (c == 1) {
#pragma unroll
            for (int k = 0; k < 4; ++k) { accB[k][0] += v[k][0]; accB[k][1] += v[k][1]; }
        } else {
#pragma unroll
            for (int k = 0; k < 4; ++k) { accC[k][0] += v[k][0]; accC[k][1] += v[k][1]; }
        }
    }

    // ---- stage 2: sample src (zeros mode), lanes vary w -> coalesced store ----
#pragma unroll
    for (int j = 0; j < 2; ++j) {
        const int h = h0 + j;
#pragma unroll
        for (int k = 0; k < 4; ++k) {
            const int d = d0 + dbase + 8 * k;
            const float f0 = (float)d + accA[k][j] * rf;   // -> x axis of src
            const float f1 = (float)h + accB[k][j] * rf;   // -> y axis
            const float f2 = (float)w + accC[k][j] * rf;   // -> z axis

            const float xs = f0 * (159.0f / 95.0f);
            const float ys = f1;
            const float zs = f2 * (95.0f / 159.0f);

            const float xs0f = floorf(xs), ys0f = floorf(ys), zs0f = floorf(zs);
            const float gx = xs - xs0f, gy = ys - ys0f, gz = zs - zs0f;
            const int xi0 = (int)xs0f, yi0 = (int)ys0f, zi0 = (int)zs0f;
            const int xi1 = xi0 + 1, yi1 = yi0 + 1, zi1 = zi0 + 1;

            auto samp = [&](int zi, int yi, int xi, float wt) -> float {
                bool valid = ((unsigned)zi < (unsigned)Dz)
                           & ((unsigned)yi < (unsigned)Hy)
                           & ((unsigned)xi < (unsigned)Wx);
                int zc = min(max(zi, 0), Dz - 1);
                int yc = min(max(yi, 0), Hy - 1);
                int xc = min(max(xi, 0), Wx - 1);
                float v = src[(zc * Hy + yc) * Wx + xc];
                return valid ? wt * v : 0.0f;
            };

            float r = samp(zi0, yi0, xi0, (1.0f - gz) * (1.0f - gy) * (1.0f - gx))
                    + samp(zi0, yi0, xi1, (1.0f - gz) * (1.0f - gy) * gx)
                    + samp(zi0, yi1, xi0, (1.0f - gz) * gy * (1.0f - gx))
                    + samp(zi0, yi1, xi1, (1.0f - gz) * gy * gx)
                    + samp(zi1, yi0, xi0, gz * (1.0f - gy) * (1.0f - gx))
                    + samp(zi1, yi0, xi1, gz * (1.0f - gy) * gx)
                    + samp(zi1, yi1, xi0, gz * gy * (1.0f - gx))
                    + samp(zi1, yi1, xi1, gz * gy * gx);

            out[(d * Hy + h) * Wx + w] = r;
        }
    }
}

extern "C" void kernel_launch(void* const* d_in, const int* in_sizes, int n_in,
                              void* d_out, int out_size, void* d_ws, size_t ws_size,
                              hipStream_t stream) {
    const float* src   = (const float*)d_in[0];
    const float* flows = (const float*)d_in[1];
    const float* rfp   = (const float*)d_in[2];
    float* out = (float*)d_out;

    st_fused_kernel<<<dim3(1200), 256, 0, stream>>>(src, flows, rfp, out);
}